// Round 16
// baseline (329.386 us; speedup 1.0000x reference)
//
#include <hip/hip_runtime.h>

typedef __attribute__((ext_vector_type(4))) float f32x4;
typedef __attribute__((ext_vector_type(8))) short s16x8;
typedef unsigned int u32;
typedef unsigned short ushort;

#define XDIM 440
#define ODIM 220
#define RPB  128         // rows per block (8 waves x 16 rows, wave-private)
#define TPB  512
#define AW   52          // Act row stride (floats): 48 data + 4 pad, 16B-aligned rows

// ---------- split helpers ----------
__device__ __forceinline__ u32 cvtpk(float a, float b){
    u32 r; asm("v_cvt_pk_bf16_f32 %0, %1, %2" : "=v"(r) : "v"(a), "v"(b)); return r;
}
// split 8 f32 -> bf16 hi/lo fragments (hi=rne(v), lo=rne(v-hi); v-hi exact)
__device__ __forceinline__ void split8pk(const float* v, s16x8& h, s16x8& l){
    uint4 hu, lu; u32* hp=(u32*)&hu; u32* lp=(u32*)&lu;
    #pragma unroll
    for (int j=0;j<4;++j){
        u32 hk = cvtpk(v[2*j], v[2*j+1]);
        float h0 = __builtin_bit_cast(float, hk<<16);
        float h1 = __builtin_bit_cast(float, hk & 0xFFFF0000u);
        lp[j] = cvtpk(v[2*j]-h0, v[2*j+1]-h1);
        hp[j] = hk;
    }
    h = __builtin_bit_cast(s16x8,hu); l = __builtin_bit_cast(s16x8,lu);
}
__device__ __forceinline__ void ldsplit(const float* p, s16x8& h, s16x8& l){
    float a[8];
    *(float4*)(a)   = *(const float4*)(p);
    *(float4*)(a+4) = *(const float4*)(p+4);
    split8pk(a,h,l);
}
__device__ __forceinline__ s16x8 ld8u(const ushort* p){ return *(const s16x8*)p; }

// D += A*B, split-bf16: AhBh + AhBl + AlBh (AlBl dropped, ~2^-18)
__device__ __forceinline__ f32x4 mm3(s16x8 ah, s16x8 al, s16x8 bh, s16x8 bl, f32x4 c){
    c = __builtin_amdgcn_mfma_f32_16x16x32_bf16(ah, bh, c, 0, 0, 0);
    c = __builtin_amdgcn_mfma_f32_16x16x32_bf16(ah, bl, c, 0, 0, 0);
    c = __builtin_amdgcn_mfma_f32_16x16x32_bf16(al, bh, c, 0, 0, 0);
    return c;
}

__device__ __forceinline__ ushort bf_rne(float f){
    unsigned u = __builtin_bit_cast(unsigned, f);
    return (ushort)((u + 0x7FFFu + ((u >> 16) & 1u)) >> 16);
}

// ---------- weight prep ----------
// WH/WL row-major [240][64] (big net rows 0..111), BIAS[240].
// WF (small net, LDS image, 12680 shorts):
//   WF0 @0    : 16 frags (t2*2+hf) x [lane 0..63][8]   -- ks=0 (k 0..31)
//   WF1 @8192 : [lane 0..31][stride 136: 16 frags x 8 + pad] -- ks=1 (k 32..47)
//               + zero block @8192+32*136 (136 shorts) for lanes >=32 (k 48..63 = 0)
__global__ void prep_w(const float* __restrict__ bW1, const float* __restrict__ bW2,
                       const float* __restrict__ bW3, const float* __restrict__ sW1,
                       const float* __restrict__ sW2, const float* __restrict__ sW3,
                       const float* __restrict__ bb1, const float* __restrict__ bb2,
                       const float* __restrict__ bb3, const float* __restrict__ sb1,
                       const float* __restrict__ sb2, const float* __restrict__ sb3,
                       ushort* __restrict__ WH, ushort* __restrict__ WL,
                       float* __restrict__ BIAS, ushort* __restrict__ WF)
{
    int i = blockIdx.x * 256 + threadIdx.x;
    if (i < 15360) {
        int n = i >> 6, k = i & 63;
        float w = 0.f;
        if      (n < 48)  { int r = n;     if (r < 40 && k < 40) w = bW1[r*40+k]; }
        else if (n < 96)  { int r = n-48;  if (r < 40 && k < 40) w = bW2[r*40+k]; }
        else if (n < 112) { int r = n-96;  if (r < 10 && k < 40) w = bW3[r*40+k]; }
        else if (n < 160) { int r = n-112; if (r < 41 && k < 41) w = sW1[r*41+k]; }
        else if (n < 208) { int r = n-160; if (r < 41 && k < 41) w = sW2[r*41+k]; }
        else              { int r = n-208; if (r < 22 && k < 41) w = sW3[r*41+k]; }
        ushort h = bf_rne(w);
        float hf = __builtin_bit_cast(float, ((unsigned)h) << 16);
        WH[i] = h; WL[i] = bf_rne(w - hf);
    } else if (i < 15600) {
        int n = i - 15360;
        float b;
        if      (n < 48)  b = (n     < 40) ? bb1[n]     : 0.f;
        else if (n < 96)  b = (n-48  < 40) ? bb2[n-48]  : 0.f;
        else if (n < 112) b = (n-96  < 10) ? bb3[n-96]  : -1e30f;
        else if (n < 160) b = (n-112 < 41) ? sb1[n-112] : 0.f;
        else if (n < 208) b = (n-160 < 41) ? sb2[n-160] : 0.f;
        else              b = (n-208 < 22) ? sb3[n-208] : -1e30f;
        BIAS[n] = b;
    } else if (i < 23792) {
        int e = i - 15600;                      // WF0: 0..8191
        int fragid = e >> 9, rem = e & 511;     // fragid = t2*2+hf
        int lane = rem >> 3, j = rem & 7;
        int t2 = fragid >> 1, hf2 = fragid & 1;
        int li = lane & 15, qq = lane >> 4;
        int r = t2*16 + li;
        int k = qq*8 + j;                       // 0..31 (< 41 always)
        float w = 0.f;
        if      (r < 48) { if (r < 41)           w = sW1[r*41+k]; }
        else if (r < 96) { int rr=r-48; if (rr<41) w = sW2[rr*41+k]; }
        else             { int rr=r-96; if (rr<22) w = sW3[rr*41+k]; }
        ushort h = bf_rne(w);
        ushort v = h;
        if (hf2){ float hfv = __builtin_bit_cast(float, ((unsigned)h)<<16); v = bf_rne(w - hfv); }
        WF[e] = v;
    } else if (i < 28280) {
        int e = i - 23792;                      // WF1 region: 0..4487 (incl. zero block)
        int lane = e / 136, c = e % 136;
        ushort v = 0;
        if (lane < 32 && c < 128){
            int fragid = c >> 3, j = c & 7;     // fragid = t2*2+hf
            int t2 = fragid >> 1, hf2 = fragid & 1;
            int li = lane & 15, qq = (lane >> 4) & 1;
            int r = t2*16 + li;
            int k = 32 + qq*8 + j;              // 32..47
            float w = 0.f;
            if      (r < 48) { if (r<41 && k<41)            w = sW1[r*41+k]; }
            else if (r < 96) { int rr=r-48; if (rr<41 && k<41) w = sW2[rr*41+k]; }
            else             { int rr=r-96; if (rr<22 && k<41) w = sW3[rr*41+k]; }
            ushort h = bf_rne(w);
            v = h;
            if (hf2){ float hfv = __builtin_bit_cast(float, ((unsigned)h)<<16); v = bf_rne(w - hfv); }
        }
        WF[8192 + e] = v;
    }
}

// NOTE: x and out deliberately NOT __restrict__: potential aliasing between
// out-stores and x-loads makes pf-reload across the flush illegal -> the
// compiler must keep the prefetched x values in registers (defeats the
// remat-eviction seen at tight launch-bounds budgets).
__global__ __launch_bounds__(TPB, 6) void ran9(
    const float* x,
    const ushort* __restrict__ WH, const ushort* __restrict__ WL,
    const float* __restrict__ BIASg, const ushort* __restrict__ WFg,
    float* out, int nrow)
{
    __shared__ ushort Wlds[12680];        // small-net weights (25360 B)
    __shared__ float  Act[RPB][AW];       // activations / out staging (26624 B)
    __shared__ float  guard[16];          // finite pad for last-row overread (64 B)
    __shared__ float  biasS[240];         // (960 B)   total 53008 B -> 52 KiB alloc
    // 3 blocks/CU x 8 waves = 24 waves/CU (needs total regs <= 85 -> bounds (512,6))

    const int tid = threadIdx.x;
    const int l   = tid & 63;
    const int w   = tid >> 6;
    const int q   = l >> 4;
    const int li  = l & 15;
    const int w16 = w * 16;
    const int R0  = blockIdx.x * RPB;
    const int arow = w16 + li;
    const int growC = min(R0 + arow, nrow - 1);
    const int wb1 = 8192 + ((l < 32) ? l*136 : 4352);   // ks=1 frag base (lanes>=32 -> zeros)

    // ---- startup: weights+bias -> LDS, zero Act+guard (NaN-proofing) ----
    {
        const u32* src = (const u32*)WFg;
        u32* dst = (u32*)Wlds;
        for (int i = tid; i < 6340; i += TPB) dst[i] = src[i];
    }
    for (int i = tid; i < 240; i += TPB) biasS[i] = BIASg[i];
    for (int i = tid; i < RPB*AW; i += TPB) ((float*)Act)[i] = 0.f;
    if (tid < 16) guard[tid] = 0.f;
    __syncthreads();                               // the ONLY barrier

#define WF0(t2,hf) (*(const s16x8*)&Wlds[((t2)*2+(hf))*512 + l*8])
#define WF1(t2,hf) (*(const s16x8*)&Wlds[wb1 + ((t2)*2+(hf))*8])

    float pm[4];   // big-net softmax for this lane's acc rows (col = li, row = w16+q*4+r)

    // ================= BIG NET (all wave-private) =================
    {   // L1 direct from x
        const float* xp = x + (size_t)growC * XDIM;
        float a0[8], a1[8];
        *(float4*)(a0)   = *(const float4*)(xp + q*8);
        *(float4*)(a0+4) = *(const float4*)(xp + q*8 + 4);
        if (q == 0){
            *(float4*)(a1)   = *(const float4*)(xp + 32);
            *(float4*)(a1+4) = *(const float4*)(xp + 36);
        } else {
            #pragma unroll
            for (int j=0;j<8;++j) a1[j] = 0.f;
        }
        s16x8 ah0,al0,ah1,al1;
        split8pk(a0, ah0, al0); split8pk(a1, ah1, al1);
        #pragma unroll
        for (int nt=0; nt<3; ++nt){
            int n = nt*16 + li; float b = biasS[n];
            f32x4 acc = {b,b,b,b};
            acc = mm3(ah0,al0, ld8u(WH+n*64+q*8),    ld8u(WL+n*64+q*8),    acc);
            acc = mm3(ah1,al1, ld8u(WH+n*64+32+q*8), ld8u(WL+n*64+32+q*8), acc);
            #pragma unroll
            for (int r=0;r<4;++r)
                Act[w16+q*4+r][nt*16+li] = fmaxf(acc[r],0.f);
        }
    }
    {   // L2  (A cols 48..63 read finite pad/next-row; big-net weights k>=48 are zero)
        s16x8 ah0,al0,ah1,al1;
        ldsplit(&Act[arow][q*8],    ah0, al0);
        ldsplit(&Act[arow][32+q*8], ah1, al1);
        #pragma unroll
        for (int nt=0; nt<3; ++nt){
            int n = 48+nt*16+li; float b = biasS[n];
            f32x4 acc = {b,b,b,b};
            acc = mm3(ah0,al0, ld8u(WH+n*64+q*8),    ld8u(WL+n*64+q*8),    acc);
            acc = mm3(ah1,al1, ld8u(WH+n*64+32+q*8), ld8u(WL+n*64+32+q*8), acc);
            #pragma unroll
            for (int r=0;r<4;++r)
                Act[w16+q*4+r][nt*16+li] = fmaxf(acc[r],0.f);
        }
    }
    {   // L3 + softmax -> pm registers (no LDS)
        s16x8 ah0,al0,ah1,al1;
        ldsplit(&Act[arow][q*8],    ah0, al0);
        ldsplit(&Act[arow][32+q*8], ah1, al1);
        int n = 96+li; float b = biasS[n];
        f32x4 acc = {b,b,b,b};
        acc = mm3(ah0,al0, ld8u(WH+n*64+q*8),    ld8u(WL+n*64+q*8),    acc);
        acc = mm3(ah1,al1, ld8u(WH+n*64+32+q*8), ld8u(WL+n*64+32+q*8), acc);
        #pragma unroll
        for (int r=0;r<4;++r){
            float v = acc[r];
            float m = v;
            m = fmaxf(m, __shfl_xor(m,1)); m = fmaxf(m, __shfl_xor(m,2));
            m = fmaxf(m, __shfl_xor(m,4)); m = fmaxf(m, __shfl_xor(m,8));
            float e = __expf(v - m);
            float sum = e;
            sum += __shfl_xor(sum,1); sum += __shfl_xor(sum,2);
            sum += __shfl_xor(sum,4); sum += __shfl_xor(sum,8);
            pm[r] = __fdividef(e, sum);       // valid for li<10; finite for all lanes
        }
    }

    // ---- per-lane x prefetch: single buffer, loaded one slot ahead ----
    const float* xrow = x + (size_t)growC * XDIM + 40;
    float pf0[8], pf1[8];
    #pragma unroll
    for (int j=0;j<8;++j) pf1[j] = 0.f;              // q!=0 lanes keep zeros
    {
        const float* xp = xrow;
        *(float4*)(pf0)   = *(const float4*)(xp + q*8);
        *(float4*)(pf0+4) = *(const float4*)(xp + q*8 + 4);
        if (q == 0){
            *(float4*)(pf1)   = *(const float4*)(xp + 32);
            *(float4*)(pf1+4) = *(const float4*)(xp + 36);
        }
    }

    #pragma unroll 1
    for (int s = 0; s < 10; ++s){
        s16x8 ah0,al0,ah1,al1;
        // iab for row w16+li: held by lane (li>>2)*16+s in pm[li&3]
        int srcl = ((li & 12) << 2) + s;
        float t0 = __shfl(pm[0], srcl);
        float t1 = __shfl(pm[1], srcl);
        float t2 = __shfl(pm[2], srcl);
        float t3 = __shfl(pm[3], srcl);
        float iv = (li & 2) ? ((li & 1) ? t3 : t2) : ((li & 1) ? t1 : t0);
        // L1 fragments from pf (pf dies here)
        split8pk(pf0, ah0, al0);
        float a1v[8];
        #pragma unroll
        for (int j=0;j<8;++j) a1v[j] = pf1[j];       // q!=0 lanes are zeros already
        if (q == 1) a1v[0] = iv;                     // k=40 = iab
        split8pk(a1v, ah1, al1);
        // prefetch next slot into the (now dead) pf buffer; cannot sink past
        // the flush stores below (possible aliasing with out)
        if (s < 9){
            const float* xp = xrow + (s+1)*40;
            *(float4*)(pf0)   = *(const float4*)(xp + q*8);
            *(float4*)(pf0+4) = *(const float4*)(xp + q*8 + 4);
            if (q == 0){
                *(float4*)(pf1)   = *(const float4*)(xp + 32);
                *(float4*)(pf1+4) = *(const float4*)(xp + 36);
            }
        }
        // ---- L1 MFMAs ----
        #pragma unroll
        for (int nt=0; nt<3; ++nt){
            float b = biasS[112+nt*16+li];
            f32x4 acc = {b,b,b,b};
            acc = mm3(ah0,al0, WF0(nt,0), WF0(nt,1), acc);
            acc = mm3(ah1,al1, WF1(nt,0), WF1(nt,1), acc);
            #pragma unroll
            for (int r=0;r<4;++r)
                Act[w16+q*4+r][nt*16+li] = fmaxf(acc[r],0.f);
        }
        // ---- L2 ----
        ldsplit(&Act[arow][q*8],    ah0, al0);
        ldsplit(&Act[arow][32+q*8], ah1, al1);
        #pragma unroll
        for (int nt=0; nt<3; ++nt){
            float b = biasS[160+nt*16+li];
            f32x4 acc = {b,b,b,b};
            acc = mm3(ah0,al0, WF0(3+nt,0), WF0(3+nt,1), acc);
            acc = mm3(ah1,al1, WF1(3+nt,0), WF1(3+nt,1), acc);
            #pragma unroll
            for (int r=0;r<4;++r)
                Act[w16+q*4+r][nt*16+li] = fmaxf(acc[r],0.f);
        }
        // ---- L3 + softmax*iab -> stage in Act cols 0..21 -> out ----
        ldsplit(&Act[arow][q*8],    ah0, al0);
        ldsplit(&Act[arow][32+q*8], ah1, al1);
        float b6 = biasS[208+li], b7 = biasS[224+li];
        f32x4 a6 = {b6,b6,b6,b6}, a7 = {b7,b7,b7,b7};
        a6 = mm3(ah0,al0, WF0(6,0), WF0(6,1), a6);
        a6 = mm3(ah1,al1, WF1(6,0), WF1(6,1), a6);
        a7 = mm3(ah0,al0, WF0(7,0), WF0(7,1), a7);
        a7 = mm3(ah1,al1, WF1(7,0), WF1(7,1), a7);
        #pragma unroll
        for (int r=0;r<4;++r){
            float v0 = a6[r], v1 = a7[r];
            float m = fmaxf(v0, v1);
            m = fmaxf(m, __shfl_xor(m,1)); m = fmaxf(m, __shfl_xor(m,2));
            m = fmaxf(m, __shfl_xor(m,4)); m = fmaxf(m, __shfl_xor(m,8));
            float e0 = __expf(v0 - m), e1 = __expf(v1 - m);
            float sum = e0 + e1;
            sum += __shfl_xor(sum,1); sum += __shfl_xor(sum,2);
            sum += __shfl_xor(sum,4); sum += __shfl_xor(sum,8);
            // iab for row w16+q*4+r: held by lane q*16+s in pm[r]
            float ivr = __shfl(pm[r], (l & 48) + s);
            float sc = __fdividef(ivr, sum);
            int lr = w16 + q*4 + r;
            Act[lr][li] = e0 * sc;                   // Act rows are dead here
            if (li < 6) Act[lr][16 + li] = e1 * sc;
        }
        // wave-private flush: 16 rows x 11 float2 chunks
        #pragma unroll
        for (int it = 0; it < 3; ++it){
            int i = l + 64*it;
            if (i < 176){
                int lr = i/11, pc = i - lr*11;
                if (R0 + w16 + lr < nrow)
                    *(float2*)(out + (size_t)(R0+w16+lr)*ODIM + s*22 + pc*2)
                        = *(const float2*)&Act[w16+lr][pc*2];
            }
        }
    }
#undef WF0
#undef WF1
    (void)guard;
}

extern "C" void kernel_launch(void* const* d_in, const int* in_sizes, int n_in,
                              void* d_out, int out_size, void* d_ws, size_t ws_size,
                              hipStream_t stream)
{
    (void)n_in; (void)out_size; (void)ws_size;
    const float* x   = (const float*)d_in[0];
    const float* bW1 = (const float*)d_in[1];
    const float* bb1 = (const float*)d_in[2];
    const float* bW2 = (const float*)d_in[3];
    const float* bb2 = (const float*)d_in[4];
    const float* bW3 = (const float*)d_in[5];
    const float* bb3 = (const float*)d_in[6];
    const float* sW1 = (const float*)d_in[7];
    const float* sb1 = (const float*)d_in[8];
    const float* sW2 = (const float*)d_in[9];
    const float* sb2 = (const float*)d_in[10];
    const float* sW3 = (const float*)d_in[11];
    const float* sb3 = (const float*)d_in[12];
    float* outp = (float*)d_out;

    ushort* WH  = (ushort*)d_ws;                        // [240][64]
    ushort* WL  = WH + 15360;                           // [240][64]
    float*  BIAS= (float*)((char*)d_ws + 61440);        // [240]
    ushort* WF  = (ushort*)((char*)d_ws + 62464);       // 12680 shorts (LDS image)

    const int rows = in_sizes[0] / XDIM;                // 262144

    prep_w<<<111, 256, 0, stream>>>(bW1, bW2, bW3, sW1, sW2, sW3,
                                    bb1, bb2, bb3, sb1, sb2, sb3,
                                    WH, WL, BIAS, WF);

    const int grid = (rows + RPB - 1) / RPB;            // 2048
    ran9<<<grid, TPB, 0, stream>>>(x, WH, WL, BIAS, WF, outp, rows);
}

// Round 18
// 291.193 us; speedup vs baseline: 1.1312x; 1.1312x over previous
//
#include <hip/hip_runtime.h>

typedef __attribute__((ext_vector_type(4))) float f32x4;
typedef __attribute__((ext_vector_type(8))) short s16x8;
typedef unsigned int u32;
typedef unsigned short ushort;

#define XDIM 440
#define ODIM 220
#define RPB  128         // rows per block (8 waves x 16 rows, wave-private)
#define TPB  512
#define AW   52          // Act row stride (floats): 48 data + 4 pad, 16B-aligned rows

// ---------- split helpers ----------
__device__ __forceinline__ u32 cvtpk(float a, float b){
    u32 r; asm("v_cvt_pk_bf16_f32 %0, %1, %2" : "=v"(r) : "v"(a), "v"(b)); return r;
}
// split 8 f32 -> bf16 hi/lo fragments (hi=rne(v), lo=rne(v-hi); v-hi exact)
__device__ __forceinline__ void split8pk(const float* v, s16x8& h, s16x8& l){
    uint4 hu, lu; u32* hp=(u32*)&hu; u32* lp=(u32*)&lu;
    #pragma unroll
    for (int j=0;j<4;++j){
        u32 hk = cvtpk(v[2*j], v[2*j+1]);
        float h0 = __builtin_bit_cast(float, hk<<16);
        float h1 = __builtin_bit_cast(float, hk & 0xFFFF0000u);
        lp[j] = cvtpk(v[2*j]-h0, v[2*j+1]-h1);
        hp[j] = hk;
    }
    h = __builtin_bit_cast(s16x8,hu); l = __builtin_bit_cast(s16x8,lu);
}
__device__ __forceinline__ void ldsplit(const float* p, s16x8& h, s16x8& l){
    float a[8];
    *(float4*)(a)   = *(const float4*)(p);
    *(float4*)(a+4) = *(const float4*)(p+4);
    split8pk(a,h,l);
}
__device__ __forceinline__ s16x8 ld8u(const ushort* p){ return *(const s16x8*)p; }

// D += A*B, split-bf16: AhBh + AhBl + AlBh (AlBl dropped, ~2^-18)
__device__ __forceinline__ f32x4 mm3(s16x8 ah, s16x8 al, s16x8 bh, s16x8 bl, f32x4 c){
    c = __builtin_amdgcn_mfma_f32_16x16x32_bf16(ah, bh, c, 0, 0, 0);
    c = __builtin_amdgcn_mfma_f32_16x16x32_bf16(ah, bl, c, 0, 0, 0);
    c = __builtin_amdgcn_mfma_f32_16x16x32_bf16(al, bh, c, 0, 0, 0);
    return c;
}

__device__ __forceinline__ ushort bf_rne(float f){
    unsigned u = __builtin_bit_cast(unsigned, f);
    return (ushort)((u + 0x7FFFu + ((u >> 16) & 1u)) >> 16);
}

// ---------- weight prep ----------
// WH/WL row-major [240][64] (big net rows 0..111), BIAS[240].
// WF (small net, LDS image, 12680 shorts):
//   WF0 @0    : 16 frags (t2*2+hf) x [lane 0..63][8]   -- ks=0 (k 0..31)
//   WF1 @8192 : [lane 0..31][stride 136: 16 frags x 8 + pad] -- ks=1 (k 32..47)
//               + zero block @8192+32*136 (136 shorts) for lanes >=32 (k 48..63 = 0)
__global__ void prep_w(const float* __restrict__ bW1, const float* __restrict__ bW2,
                       const float* __restrict__ bW3, const float* __restrict__ sW1,
                       const float* __restrict__ sW2, const float* __restrict__ sW3,
                       const float* __restrict__ bb1, const float* __restrict__ bb2,
                       const float* __restrict__ bb3, const float* __restrict__ sb1,
                       const float* __restrict__ sb2, const float* __restrict__ sb3,
                       ushort* __restrict__ WH, ushort* __restrict__ WL,
                       float* __restrict__ BIAS, ushort* __restrict__ WF)
{
    int i = blockIdx.x * 256 + threadIdx.x;
    if (i < 15360) {
        int n = i >> 6, k = i & 63;
        float w = 0.f;
        if      (n < 48)  { int r = n;     if (r < 40 && k < 40) w = bW1[r*40+k]; }
        else if (n < 96)  { int r = n-48;  if (r < 40 && k < 40) w = bW2[r*40+k]; }
        else if (n < 112) { int r = n-96;  if (r < 10 && k < 40) w = bW3[r*40+k]; }
        else if (n < 160) { int r = n-112; if (r < 41 && k < 41) w = sW1[r*41+k]; }
        else if (n < 208) { int r = n-160; if (r < 41 && k < 41) w = sW2[r*41+k]; }
        else              { int r = n-208; if (r < 22 && k < 41) w = sW3[r*41+k]; }
        ushort h = bf_rne(w);
        float hf = __builtin_bit_cast(float, ((unsigned)h) << 16);
        WH[i] = h; WL[i] = bf_rne(w - hf);
    } else if (i < 15600) {
        int n = i - 15360;
        float b;
        if      (n < 48)  b = (n     < 40) ? bb1[n]     : 0.f;
        else if (n < 96)  b = (n-48  < 40) ? bb2[n-48]  : 0.f;
        else if (n < 112) b = (n-96  < 10) ? bb3[n-96]  : -1e30f;
        else if (n < 160) b = (n-112 < 41) ? sb1[n-112] : 0.f;
        else if (n < 208) b = (n-160 < 41) ? sb2[n-160] : 0.f;
        else              b = (n-208 < 22) ? sb3[n-208] : -1e30f;
        BIAS[n] = b;
    } else if (i < 23792) {
        int e = i - 15600;                      // WF0: 0..8191
        int fragid = e >> 9, rem = e & 511;     // fragid = t2*2+hf
        int lane = rem >> 3, j = rem & 7;
        int t2 = fragid >> 1, hf2 = fragid & 1;
        int li = lane & 15, qq = lane >> 4;
        int r = t2*16 + li;
        int k = qq*8 + j;                       // 0..31 (< 41 always)
        float w = 0.f;
        if      (r < 48) { if (r < 41)           w = sW1[r*41+k]; }
        else if (r < 96) { int rr=r-48; if (rr<41) w = sW2[rr*41+k]; }
        else             { int rr=r-96; if (rr<22) w = sW3[rr*41+k]; }
        ushort h = bf_rne(w);
        ushort v = h;
        if (hf2){ float hfv = __builtin_bit_cast(float, ((unsigned)h)<<16); v = bf_rne(w - hfv); }
        WF[e] = v;
    } else if (i < 28280) {
        int e = i - 23792;                      // WF1 region: 0..4487 (incl. zero block)
        int lane = e / 136, c = e % 136;
        ushort v = 0;
        if (lane < 32 && c < 128){
            int fragid = c >> 3, j = c & 7;     // fragid = t2*2+hf
            int t2 = fragid >> 1, hf2 = fragid & 1;
            int li = lane & 15, qq = (lane >> 4) & 1;
            int r = t2*16 + li;
            int k = 32 + qq*8 + j;              // 32..47
            float w = 0.f;
            if      (r < 48) { if (r<41 && k<41)            w = sW1[r*41+k]; }
            else if (r < 96) { int rr=r-48; if (rr<41 && k<41) w = sW2[rr*41+k]; }
            else             { int rr=r-96; if (rr<22 && k<41) w = sW3[rr*41+k]; }
            ushort h = bf_rne(w);
            v = h;
            if (hf2){ float hfv = __builtin_bit_cast(float, ((unsigned)h)<<16); v = bf_rne(w - hfv); }
        }
        WF[8192 + e] = v;
    }
}

__global__ __launch_bounds__(TPB, 4) void ran11(
    const float* __restrict__ x,
    const ushort* __restrict__ WH, const ushort* __restrict__ WL,
    const float* __restrict__ BIASg, const ushort* __restrict__ WFg,
    float* __restrict__ out, int nrow)
{
    // explicit layout: guard row after Act so stride-52 overreads stay finite
    __shared__ ushort Wlds[12680];        // small-net weights (25360 B)
    __shared__ float  Act[RPB][AW];       // activations / out staging (26624 B)
    __shared__ float  guard[16];          // finite pad for last-row overread (64 B)
    __shared__ float  biasS[240];         // (960 B)   total 53008 B -> 52 KiB alloc

    const int tid = threadIdx.x;
    const int l   = tid & 63;
    const int w   = tid >> 6;
    const int q   = l >> 4;
    const int li  = l & 15;
    const int w16 = w * 16;
    const int R0  = blockIdx.x * RPB;
    const int arow = w16 + li;
    const int growC = min(R0 + arow, nrow - 1);
    const int wb1 = 8192 + ((l < 32) ? l*136 : 4352);   // ks=1 frag base (lanes>=32 -> zeros)

    // ---- startup: weights+bias -> LDS, zero Act+guard (NaN-proofing) ----
    {
        const u32* src = (const u32*)WFg;
        u32* dst = (u32*)Wlds;
        for (int i = tid; i < 6340; i += TPB) dst[i] = src[i];
    }
    for (int i = tid; i < 240; i += TPB) biasS[i] = BIASg[i];
    for (int i = tid; i < RPB*AW; i += TPB) ((float*)Act)[i] = 0.f;
    if (tid < 16) guard[tid] = 0.f;
    __syncthreads();                               // the ONLY barrier

#define WF0(t2,hf) (*(const s16x8*)&Wlds[((t2)*2+(hf))*512 + l*8])
#define WF1(t2,hf) (*(const s16x8*)&Wlds[wb1 + ((t2)*2+(hf))*8])
#define PRIO_HI __builtin_amdgcn_s_setprio(1)
#define PRIO_LO __builtin_amdgcn_s_setprio(0)

    float pm[4];   // big-net softmax for this lane's acc rows (col = li, row = w16+q*4+r)

    // ================= BIG NET (all wave-private) =================
    {   // L1 direct from x
        const float* xp = x + (size_t)growC * XDIM;
        float a0[8], a1[8];
        *(float4*)(a0)   = *(const float4*)(xp + q*8);
        *(float4*)(a0+4) = *(const float4*)(xp + q*8 + 4);
        if (q == 0){
            *(float4*)(a1)   = *(const float4*)(xp + 32);
            *(float4*)(a1+4) = *(const float4*)(xp + 36);
        } else {
            #pragma unroll
            for (int j=0;j<8;++j) a1[j] = 0.f;
        }
        s16x8 ah0,al0,ah1,al1;
        split8pk(a0, ah0, al0); split8pk(a1, ah1, al1);
        PRIO_HI;
        #pragma unroll
        for (int nt=0; nt<3; ++nt){
            int n = nt*16 + li; float b = biasS[n];
            f32x4 acc = {b,b,b,b};
            acc = mm3(ah0,al0, ld8u(WH+n*64+q*8),    ld8u(WL+n*64+q*8),    acc);
            acc = mm3(ah1,al1, ld8u(WH+n*64+32+q*8), ld8u(WL+n*64+32+q*8), acc);
            #pragma unroll
            for (int r=0;r<4;++r)
                Act[w16+q*4+r][nt*16+li] = fmaxf(acc[r],0.f);
        }
        PRIO_LO;
    }
    {   // L2  (A cols 48..63 read finite pad/next-row; big-net weights k>=48 are zero)
        s16x8 ah0,al0,ah1,al1;
        ldsplit(&Act[arow][q*8],    ah0, al0);
        ldsplit(&Act[arow][32+q*8], ah1, al1);
        PRIO_HI;
        #pragma unroll
        for (int nt=0; nt<3; ++nt){
            int n = 48+nt*16+li; float b = biasS[n];
            f32x4 acc = {b,b,b,b};
            acc = mm3(ah0,al0, ld8u(WH+n*64+q*8),    ld8u(WL+n*64+q*8),    acc);
            acc = mm3(ah1,al1, ld8u(WH+n*64+32+q*8), ld8u(WL+n*64+32+q*8), acc);
            #pragma unroll
            for (int r=0;r<4;++r)
                Act[w16+q*4+r][nt*16+li] = fmaxf(acc[r],0.f);
        }
        PRIO_LO;
    }
    {   // L3 + softmax -> pm registers (no LDS)
        s16x8 ah0,al0,ah1,al1;
        ldsplit(&Act[arow][q*8],    ah0, al0);
        ldsplit(&Act[arow][32+q*8], ah1, al1);
        int n = 96+li; float b = biasS[n];
        f32x4 acc = {b,b,b,b};
        PRIO_HI;
        acc = mm3(ah0,al0, ld8u(WH+n*64+q*8),    ld8u(WL+n*64+q*8),    acc);
        acc = mm3(ah1,al1, ld8u(WH+n*64+32+q*8), ld8u(WL+n*64+32+q*8), acc);
        PRIO_LO;
        #pragma unroll
        for (int r=0;r<4;++r){
            float v = acc[r];
            float m = v;
            m = fmaxf(m, __shfl_xor(m,1)); m = fmaxf(m, __shfl_xor(m,2));
            m = fmaxf(m, __shfl_xor(m,4)); m = fmaxf(m, __shfl_xor(m,8));
            float e = __expf(v - m);
            float sum = e;
            sum += __shfl_xor(sum,1); sum += __shfl_xor(sum,2);
            sum += __shfl_xor(sum,4); sum += __shfl_xor(sum,8);
            pm[r] = __fdividef(e, sum);       // valid for li<10; finite for all lanes
        }
    }

    // ---- per-lane x prefetch (slot inputs in registers) ----
    const float* xrow = x + (size_t)growC * XDIM + 40;
    auto stage_load = [&](int S, float* pf0, float* pf1){
        const float* xp = xrow + S*40;
        *(float4*)(pf0)   = *(const float4*)(xp + q*8);
        *(float4*)(pf0+4) = *(const float4*)(xp + q*8 + 4);
        if (q == 0){
            *(float4*)(pf1)   = *(const float4*)(xp + 32);
            *(float4*)(pf1+4) = *(const float4*)(xp + 36);
        }
    };

    auto compute_slot = [&](int s, const float* pf0, const float* pf1){
        s16x8 ah0,al0,ah1,al1;
        // iab for row w16+li: held by lane (li>>2)*16+s in pm[li&3]
        int srcl = ((li & 12) << 2) + s;
        float t0 = __shfl(pm[0], srcl);
        float t1 = __shfl(pm[1], srcl);
        float t2 = __shfl(pm[2], srcl);
        float t3 = __shfl(pm[3], srcl);
        float iv = (li & 2) ? ((li & 1) ? t3 : t2) : ((li & 1) ? t1 : t0);
        // L1: fragments from registers + iab
        split8pk(pf0, ah0, al0);
        float a1v[8];
        #pragma unroll
        for (int j=0;j<8;++j) a1v[j] = (q==0) ? pf1[j] : 0.f;
        if (q == 1) a1v[0] = iv;                     // k=40 = iab
        split8pk(a1v, ah1, al1);
        PRIO_HI;
        #pragma unroll
        for (int nt=0; nt<3; ++nt){
            float b = biasS[112+nt*16+li];
            f32x4 acc = {b,b,b,b};
            acc = mm3(ah0,al0, WF0(nt,0), WF0(nt,1), acc);
            acc = mm3(ah1,al1, WF1(nt,0), WF1(nt,1), acc);
            #pragma unroll
            for (int r=0;r<4;++r)
                Act[w16+q*4+r][nt*16+li] = fmaxf(acc[r],0.f);
        }
        PRIO_LO;
        // L2
        ldsplit(&Act[arow][q*8],    ah0, al0);
        ldsplit(&Act[arow][32+q*8], ah1, al1);
        PRIO_HI;
        #pragma unroll
        for (int nt=0; nt<3; ++nt){
            float b = biasS[160+nt*16+li];
            f32x4 acc = {b,b,b,b};
            acc = mm3(ah0,al0, WF0(3+nt,0), WF0(3+nt,1), acc);
            acc = mm3(ah1,al1, WF1(3+nt,0), WF1(3+nt,1), acc);
            #pragma unroll
            for (int r=0;r<4;++r)
                Act[w16+q*4+r][nt*16+li] = fmaxf(acc[r],0.f);
        }
        PRIO_LO;
        // L3 + softmax*iab -> stage in Act cols 0..21 -> out
        ldsplit(&Act[arow][q*8],    ah0, al0);
        ldsplit(&Act[arow][32+q*8], ah1, al1);
        float b6 = biasS[208+li], b7 = biasS[224+li];
        f32x4 a6 = {b6,b6,b6,b6}, a7 = {b7,b7,b7,b7};
        PRIO_HI;
        a6 = mm3(ah0,al0, WF0(6,0), WF0(6,1), a6);
        a6 = mm3(ah1,al1, WF1(6,0), WF1(6,1), a6);
        a7 = mm3(ah0,al0, WF0(7,0), WF0(7,1), a7);
        a7 = mm3(ah1,al1, WF1(7,0), WF1(7,1), a7);
        PRIO_LO;
        #pragma unroll
        for (int r=0;r<4;++r){
            float v0 = a6[r], v1 = a7[r];
            float m = fmaxf(v0, v1);
            m = fmaxf(m, __shfl_xor(m,1)); m = fmaxf(m, __shfl_xor(m,2));
            m = fmaxf(m, __shfl_xor(m,4)); m = fmaxf(m, __shfl_xor(m,8));
            float e0 = __expf(v0 - m), e1 = __expf(v1 - m);
            float sum = e0 + e1;
            sum += __shfl_xor(sum,1); sum += __shfl_xor(sum,2);
            sum += __shfl_xor(sum,4); sum += __shfl_xor(sum,8);
            // iab for row w16+q*4+r: held by lane q*16+s in pm[r]
            float ivr = __shfl(pm[r], (l & 48) + s);
            float sc = __fdividef(ivr, sum);
            int lr = w16 + q*4 + r;
            Act[lr][li] = e0 * sc;                   // Act rows are dead here
            if (li < 6) Act[lr][16 + li] = e1 * sc;
        }
        // wave-private flush: 16 rows x 11 float2 chunks
        #pragma unroll
        for (int it = 0; it < 3; ++it){
            int i = l + 64*it;
            if (i < 176){
                int lr = i/11, pc = i - lr*11;
                if (R0 + w16 + lr < nrow)
                    *(float2*)(out + (size_t)(R0+w16+lr)*ODIM + s*22 + pc*2)
                        = *(const float2*)&Act[w16+lr][pc*2];
            }
        }
    };

    float pfA0[8], pfA1[8], pfB0[8], pfB1[8];
    stage_load(0, pfA0, pfA1);
    #pragma unroll 1
    for (int s = 0; s < 10; s += 2){
        stage_load(s+1, pfB0, pfB1);                 // issue early (T14)
        compute_slot(s, pfA0, pfA1);
        if (s+2 < 10) stage_load(s+2, pfA0, pfA1);
        compute_slot(s+1, pfB0, pfB1);
    }
#undef WF0
#undef WF1
#undef PRIO_HI
#undef PRIO_LO
    (void)guard;
}

extern "C" void kernel_launch(void* const* d_in, const int* in_sizes, int n_in,
                              void* d_out, int out_size, void* d_ws, size_t ws_size,
                              hipStream_t stream)
{
    (void)n_in; (void)out_size; (void)ws_size;
    const float* x   = (const float*)d_in[0];
    const float* bW1 = (const float*)d_in[1];
    const float* bb1 = (const float*)d_in[2];
    const float* bW2 = (const float*)d_in[3];
    const float* bb2 = (const float*)d_in[4];
    const float* bW3 = (const float*)d_in[5];
    const float* bb3 = (const float*)d_in[6];
    const float* sW1 = (const float*)d_in[7];
    const float* sb1 = (const float*)d_in[8];
    const float* sW2 = (const float*)d_in[9];
    const float* sb2 = (const float*)d_in[10];
    const float* sW3 = (const float*)d_in[11];
    const float* sb3 = (const float*)d_in[12];
    float* outp = (float*)d_out;

    ushort* WH  = (ushort*)d_ws;                        // [240][64]
    ushort* WL  = WH + 15360;                           // [240][64]
    float*  BIAS= (float*)((char*)d_ws + 61440);        // [240]
    ushort* WF  = (ushort*)((char*)d_ws + 62464);       // 12680 shorts (LDS image)

    const int rows = in_sizes[0] / XDIM;                // 262144

    prep_w<<<111, 256, 0, stream>>>(bW1, bW2, bW3, sW1, sW2, sW3,
                                    bb1, bb2, bb3, sb1, sb2, sb3,
                                    WH, WL, BIAS, WF);

    const int grid = (rows + RPB - 1) / RPB;            // 2048
    ran11<<<grid, TPB, 0, stream>>>(x, WH, WL, BIAS, WF, outp, rows);
}